// Round 6
// baseline (264.525 us; speedup 1.0000x reference)
//
#include <hip/hip_runtime.h>
#include <hip/hip_bf16.h>

typedef __attribute__((ext_vector_type(8))) short bf16x8;
typedef __attribute__((ext_vector_type(4))) float f32x4;

#define CHUNK 32
#define NCHUNK 256   // 8192 / CHUNK

__device__ __forceinline__ void gload16(const void* g, void* l) {
    __builtin_amdgcn_global_load_lds(
        (const __attribute__((address_space(1))) void*)g,
        (__attribute__((address_space(3))) void*)l,
        16, 0, 0);
}

__device__ __forceinline__ float silu_f(float v) { return v / (1.0f + __expf(-v)); }

// ---------------- prep: small-weight converts + Wc = q_w @ out_proj ----------------
__global__ __launch_bounds__(256) void prep_k(
    const float* __restrict__ in_proj_w, const float* __restrict__ x_proj_w,
    const float* __restrict__ k_w, const float* __restrict__ q_w,
    const float* __restrict__ out_proj_w,
    __hip_bfloat16* __restrict__ wib, __hip_bfloat16* __restrict__ wxb,
    __hip_bfloat16* __restrict__ kwb, __hip_bfloat16* __restrict__ wcb)
{
    const int b = blockIdx.x, t = threadIdx.x;
    if (b < 424) {
        int idx = b * 256 + t;
        if (idx < 65536)      wib[idx]         = __float2bfloat16(in_proj_w[idx]);
        else if (idx < 75776) wxb[idx - 65536] = __float2bfloat16(x_proj_w[idx - 65536]);
        else                  kwb[idx - 75776] = __float2bfloat16(k_w[idx - 75776]);
    } else {
        const int hh = b - 424;
        float acc = 0.0f;
        for (int m = 0; m < 128; ++m) acc += q_w[hh * 128 + m] * out_proj_w[m * 256 + t];
        wcb[hh * 256 + t] = __float2bfloat16(acc);
    }
}

// ---------------- generic bf16 A[M,K] @ B[N,K]^T -> C[M,N] (small GEMMs) ----------------
template<int OUT_BF16, int HAS_BIAS>
__global__ __launch_bounds__(256) void gemm_bt_k(
    const __hip_bfloat16* __restrict__ A,
    const __hip_bfloat16* __restrict__ B,
    float* __restrict__ Cf, __hip_bfloat16* __restrict__ Cb,
    const float* __restrict__ bias, int M, int N, int K)
{
    __shared__ __hip_bfloat16 As[64][40];
    __shared__ __hip_bfloat16 Bs[64][40];
    const int tid  = threadIdx.x;
    const int wave = tid >> 6;
    const int lane = tid & 63;
    const int wm = (wave >> 1) << 5;
    const int wn = (wave & 1) << 5;
    const long bm = (long)blockIdx.y << 6;
    const long bn = (long)blockIdx.x << 6;

    f32x4 acc[2][2] = {{{0.f,0.f,0.f,0.f},{0.f,0.f,0.f,0.f}},
                       {{0.f,0.f,0.f,0.f},{0.f,0.f,0.f,0.f}}};

    const int sr = tid >> 2;
    const int sc = (tid & 3) << 3;
    const int lr = lane & 15;
    const int kg = (lane >> 4) << 3;

    for (int k0 = 0; k0 < K; k0 += 32) {
        {
            long ar = bm + sr;
            bf16x8 av = {0,0,0,0,0,0,0,0};
            if (ar < M) av = *(const bf16x8*)(A + ar * K + k0 + sc);
            *(bf16x8*)&As[sr][sc] = av;
            long br = bn + sr;
            bf16x8 bv = {0,0,0,0,0,0,0,0};
            if (br < N) bv = *(const bf16x8*)(B + br * K + k0 + sc);
            *(bf16x8*)&Bs[sr][sc] = bv;
        }
        __syncthreads();
        bf16x8 a0 = *(const bf16x8*)&As[wm + lr][kg];
        bf16x8 a1 = *(const bf16x8*)&As[wm + 16 + lr][kg];
        bf16x8 b0 = *(const bf16x8*)&Bs[wn + lr][kg];
        bf16x8 b1 = *(const bf16x8*)&Bs[wn + 16 + lr][kg];
        acc[0][0] = __builtin_amdgcn_mfma_f32_16x16x32_bf16(a0, b0, acc[0][0], 0, 0, 0);
        acc[0][1] = __builtin_amdgcn_mfma_f32_16x16x32_bf16(a0, b1, acc[0][1], 0, 0, 0);
        acc[1][0] = __builtin_amdgcn_mfma_f32_16x16x32_bf16(a1, b0, acc[1][0], 0, 0, 0);
        acc[1][1] = __builtin_amdgcn_mfma_f32_16x16x32_bf16(a1, b1, acc[1][1], 0, 0, 0);
        __syncthreads();
    }
    const int rg = (lane >> 4) << 2;
    #pragma unroll
    for (int i = 0; i < 2; ++i)
      #pragma unroll
      for (int j = 0; j < 2; ++j)
        #pragma unroll
        for (int r = 0; r < 4; ++r) {
            long row = bm + wm + i * 16 + rg + r;
            long col = bn + wn + j * 16 + lr;
            if (row < M && col < N) {
                float v = acc[i][j][r];
                if (HAS_BIAS) v += bias[col];
                if (OUT_BF16) Cb[row * N + col] = __float2bfloat16(v);
                else          Cf[row * N + col] = v;
            }
        }
}

// ---------------- fp32-A GEMM: A[M,K]f32 @ B[N,K]^T, staged convert to bf16 ----------------
template<int EPI>
__global__ __launch_bounds__(256) void gemm_f32a_k(
    const float* __restrict__ A, const __hip_bfloat16* __restrict__ B,
    const float* __restrict__ w0, const float* __restrict__ w1,
    float* __restrict__ xf, __hip_bfloat16* __restrict__ ob, float* __restrict__ zs,
    int M, int N, int K)
{
    __shared__ __hip_bfloat16 As[64][40];
    __shared__ __hip_bfloat16 Bs[64][40];
    const int tid  = threadIdx.x;
    const int wave = tid >> 6;
    const int lane = tid & 63;
    const int wm = (wave >> 1) << 5;
    const int wn = (wave & 1) << 5;
    const long bm = (long)blockIdx.y << 6;
    const long bn = (long)blockIdx.x << 6;

    f32x4 acc[2][2] = {{{0.f,0.f,0.f,0.f},{0.f,0.f,0.f,0.f}},
                       {{0.f,0.f,0.f,0.f},{0.f,0.f,0.f,0.f}}};

    const int sr = tid >> 2;
    const int sc = (tid & 3) << 3;
    const int lr = lane & 15;
    const int kg = (lane >> 4) << 3;

    for (int k0 = 0; k0 < K; k0 += 32) {
        {
            long ar = bm + sr;
            f32x4 x0 = *(const f32x4*)(A + ar * K + k0 + sc);
            f32x4 x1 = *(const f32x4*)(A + ar * K + k0 + sc + 4);
            union { bf16x8 v; __hip_bfloat16 h[8]; } u;
            u.h[0] = __float2bfloat16(x0[0]); u.h[1] = __float2bfloat16(x0[1]);
            u.h[2] = __float2bfloat16(x0[2]); u.h[3] = __float2bfloat16(x0[3]);
            u.h[4] = __float2bfloat16(x1[0]); u.h[5] = __float2bfloat16(x1[1]);
            u.h[6] = __float2bfloat16(x1[2]); u.h[7] = __float2bfloat16(x1[3]);
            *(bf16x8*)&As[sr][sc] = u.v;
            long br = bn + sr;
            bf16x8 bv = {0,0,0,0,0,0,0,0};
            if (br < N) bv = *(const bf16x8*)(B + br * K + k0 + sc);
            *(bf16x8*)&Bs[sr][sc] = bv;
        }
        __syncthreads();
        bf16x8 a0 = *(const bf16x8*)&As[wm + lr][kg];
        bf16x8 a1 = *(const bf16x8*)&As[wm + 16 + lr][kg];
        bf16x8 b0 = *(const bf16x8*)&Bs[wn + lr][kg];
        bf16x8 b1 = *(const bf16x8*)&Bs[wn + 16 + lr][kg];
        acc[0][0] = __builtin_amdgcn_mfma_f32_16x16x32_bf16(a0, b0, acc[0][0], 0, 0, 0);
        acc[0][1] = __builtin_amdgcn_mfma_f32_16x16x32_bf16(a0, b1, acc[0][1], 0, 0, 0);
        acc[1][0] = __builtin_amdgcn_mfma_f32_16x16x32_bf16(a1, b0, acc[1][0], 0, 0, 0);
        acc[1][1] = __builtin_amdgcn_mfma_f32_16x16x32_bf16(a1, b1, acc[1][1], 0, 0, 0);
        __syncthreads();
    }
    const int rg = (lane >> 4) << 2;
    #pragma unroll
    for (int i = 0; i < 2; ++i)
      #pragma unroll
      for (int j = 0; j < 2; ++j)
        #pragma unroll
        for (int r = 0; r < 4; ++r) {
            long row = bm + wm + i * 16 + rg + r;
            long col = bn + wn + j * 16 + lr;
            float v = acc[i][j][r];
            if (EPI == 0) {
                if (col < 256) {
                    float xv = v * w0[col] + w1[col];
                    float s = silu_f(xv);
                    xf[row * 256 + col] = s;
                    ob[row * 256 + col] = __float2bfloat16(s);
                } else {
                    zs[row * 256 + col - 256] = silu_f(v);
                }
            } else {
                ob[row * N + col] = __float2bfloat16(v + w0[col]);
            }
        }
}

// ---------------- scores: 256x256 tile, 8 waves, BK=64, double-buffered LDS ----------------
// Counted vmcnt(8) + raw s_barrier (prefetch stays in flight), setprio around MFMA.
// XOR swizzle: linear LDS dest, pre-swizzled global source, swizzled ds_read (rule 21).
// PASS 0: partial rowsums of exp(s) -> partial[128][8192];  PASS 1: p = exp(s)*invZ -> d_out
template<int PASS>
__global__ __launch_bounds__(512, 2) void scores_k(
    const __hip_bfloat16* __restrict__ Q, const __hip_bfloat16* __restrict__ Kb,
    float* __restrict__ out, const float* __restrict__ invZ)
{
    __shared__ alignas(16) char lds[2][2][32768];   // [buf][A=0/B=1][256 rows x 128 B]
    const int tid = threadIdx.x, wave = tid >> 6, lane = tid & 63;
    const int bm = blockIdx.y << 8, bn = blockIdx.x << 8;
    const int wr = wave >> 2, wc = wave & 3;        // wave tile: rows wr*128, cols wc*64
    const int K = 256;

    f32x4 acc[8][4];
    #pragma unroll
    for (int i = 0; i < 8; ++i)
      #pragma unroll
      for (int j = 0; j < 4; ++j)
        acc[i][j] = (f32x4){0.f, 0.f, 0.f, 0.f};

    // stage one K-slab (A[256][64] + B[256][64] bf16) into lds[buf]: 8 vmem insts/wave
    #define STAGE(buf, k0)                                                          \
        { _Pragma("unroll")                                                         \
          for (int is = 0; is < 4; ++is) {                                          \
            const int o = (is * 512 + tid) * 16;                                    \
            const int q = o ^ (((o >> 7) & 7) << 4);                                \
            const int row = o >> 7;                                                 \
            const int ce  = (q & 127) >> 1;                                         \
            gload16(Q  + (size_t)(bm + row) * K + (k0) + ce, &lds[buf][0][o]);      \
            gload16(Kb + (size_t)(bn + row) * K + (k0) + ce, &lds[buf][1][o]);      \
          } }

    #define COMPUTE(buf)                                                            \
        { _Pragma("unroll")                                                         \
          for (int ks = 0; ks < 2; ++ks) {                                          \
            const int cb = ks * 64 + ((lane >> 4) << 4);                            \
            bf16x8 bfr[4];                                                          \
            _Pragma("unroll")                                                       \
            for (int j = 0; j < 4; ++j) {                                           \
                const int rb = wc * 64 + j * 16 + (lane & 15);                      \
                bfr[j] = *(const bf16x8*)&lds[buf][1][(rb * 128 + cb) ^ ((rb & 7) << 4)]; \
            }                                                                       \
            _Pragma("unroll")                                                       \
            for (int i = 0; i < 8; ++i) {                                           \
                const int ra = wr * 128 + i * 16 + (lane & 15);                     \
                bf16x8 af = *(const bf16x8*)&lds[buf][0][(ra * 128 + cb) ^ ((ra & 7) << 4)]; \
                _Pragma("unroll")                                                   \
                for (int j = 0; j < 4; ++j)                                         \
                    acc[i][j] = __builtin_amdgcn_mfma_f32_16x16x32_bf16(af, bfr[j], acc[i][j], 0, 0, 0); \
            } } }

    STAGE(0, 0)
    // iter 0
    STAGE(1, 64)
    asm volatile("s_waitcnt vmcnt(8)" ::: "memory");
    __builtin_amdgcn_s_barrier();
    __builtin_amdgcn_s_setprio(1);
    COMPUTE(0)
    __builtin_amdgcn_s_setprio(0);
    asm volatile("s_waitcnt lgkmcnt(0)" ::: "memory");
    __builtin_amdgcn_s_barrier();
    // iter 1
    STAGE(0, 128)
    asm volatile("s_waitcnt vmcnt(8)" ::: "memory");
    __builtin_amdgcn_s_barrier();
    __builtin_amdgcn_s_setprio(1);
    COMPUTE(1)
    __builtin_amdgcn_s_setprio(0);
    asm volatile("s_waitcnt lgkmcnt(0)" ::: "memory");
    __builtin_amdgcn_s_barrier();
    // iter 2
    STAGE(1, 192)
    asm volatile("s_waitcnt vmcnt(8)" ::: "memory");
    __builtin_amdgcn_s_barrier();
    __builtin_amdgcn_s_setprio(1);
    COMPUTE(0)
    __builtin_amdgcn_s_setprio(0);
    asm volatile("s_waitcnt lgkmcnt(0)" ::: "memory");
    __builtin_amdgcn_s_barrier();
    // iter 3
    asm volatile("s_waitcnt vmcnt(0)" ::: "memory");
    __builtin_amdgcn_s_barrier();
    __builtin_amdgcn_s_setprio(1);
    COMPUTE(1)
    __builtin_amdgcn_s_setprio(0);
    #undef STAGE
    #undef COMPUTE

    const int lr = lane & 15, rg = (lane >> 4);
    if (PASS == 0) {
        #pragma unroll
        for (int i = 0; i < 8; ++i)
          #pragma unroll
          for (int r = 0; r < 4; ++r) {
            float s = __expf(acc[i][0][r]) + __expf(acc[i][1][r])
                    + __expf(acc[i][2][r]) + __expf(acc[i][3][r]);
            #pragma unroll
            for (int o = 1; o < 16; o <<= 1) s += __shfl_xor(s, o, 64);
            if (lr == 0)
                out[(size_t)(blockIdx.x * 4 + wc) * 8192
                    + bm + wr * 128 + i * 16 + rg * 4 + r] = s;
          }
    } else {
        #pragma unroll
        for (int i = 0; i < 8; ++i)
          #pragma unroll
          for (int r = 0; r < 4; ++r) {
            const int row = bm + wr * 128 + i * 16 + rg * 4 + r;
            const float iz = invZ[row];
            #pragma unroll
            for (int j = 0; j < 4; ++j)
                __builtin_nontemporal_store(__expf(acc[i][j][r]) * iz,
                    out + (size_t)row * 8192 + bn + wc * 64 + j * 16 + lr);
          }
    }
}

// ---------------- rowsum -> reciprocal ----------------
__global__ __launch_bounds__(256) void rowsum_inv_k(
    const float* __restrict__ partial, float* __restrict__ invZ)
{
    const int row = blockIdx.x * 256 + threadIdx.x;
    float s = 0.0f;
    for (int c = 0; c < 128; ++c) s += partial[(size_t)c * 8192 + row];
    invZ[row] = 1.0f / s;
}

// ---------------- scan phase A: per-chunk affine summaries (dt fused) ----------------
__global__ __launch_bounds__(256) void scan_chunk_k(
    const float* __restrict__ xf, const float* __restrict__ xdbl,
    const float* __restrict__ dtw, const float* __restrict__ dtb,
    const float* __restrict__ A_log,
    float* __restrict__ P, float* __restrict__ S)
{
    __shared__ float xs[CHUNK * 40];
    const int c = blockIdx.x, d = threadIdx.x;
    const int t0 = c * CHUNK;
    for (int k = d; k < CHUNK * 40; k += 256) xs[k] = xdbl[(size_t)t0 * 40 + k];
    __syncthreads();
    const f32x4 wa = *(const f32x4*)(dtw + d * 8);
    const f32x4 wb = *(const f32x4*)(dtw + d * 8 + 4);
    const float dbias = dtb[d];
    float An[16], Pv[16], Sv[16];
    #pragma unroll
    for (int n = 0; n < 16; ++n) { An[n] = -expf(A_log[d * 16 + n]); Pv[n] = 1.0f; Sv[n] = 0.0f; }
    for (int tt = 0; tt < CHUNK; ++tt) {
        const float* xr = xs + tt * 40;
        float dr = dbias + xr[0]*wa[0] + xr[1]*wa[1] + xr[2]*wa[2] + xr[3]*wa[3]
                         + xr[4]*wb[0] + xr[5]*wb[1] + xr[6]*wb[2] + xr[7]*wb[3];
        float dt = (dr > 20.0f) ? dr : logf(1.0f + expf(dr));
        float xv = xf[(size_t)(t0 + tt) * 256 + d];
        float dtx = dt * xv;
        #pragma unroll
        for (int n = 0; n < 16; ++n) {
            float a = __expf(dt * An[n]);
            Pv[n] *= a;
            Sv[n] = a * Sv[n] + dtx * xr[8 + n];
        }
    }
    size_t base = (size_t)c * 4096 + (size_t)d * 16;
    #pragma unroll
    for (int n = 0; n < 16; ++n) { P[base + n] = Pv[n]; S[base + n] = Sv[n]; }
}

// ---------------- scan phase B: carry across chunks (8x batched loads) ----------------
__global__ __launch_bounds__(256) void scan_carry_k(
    const float* __restrict__ P, const float* __restrict__ S, float* __restrict__ hinit)
{
    const int ch = blockIdx.x * 256 + threadIdx.x;
    float h = 0.0f;
    for (int c = 0; c < NCHUNK; c += 8) {
        float p[8], s[8];
        #pragma unroll
        for (int j = 0; j < 8; ++j) {
            p[j] = P[(size_t)(c + j) * 4096 + ch];
            s[j] = S[(size_t)(c + j) * 4096 + ch];
        }
        #pragma unroll
        for (int j = 0; j < 8; ++j) {
            hinit[(size_t)(c + j) * 4096 + ch] = h;
            h = p[j] * h + s[j];
        }
    }
}

// ---------------- scan phase C: replay + gate (dt fused) -> yfin bf16 ----------------
__global__ __launch_bounds__(256) void scan_final_k(
    const float* __restrict__ xf, const float* __restrict__ xdbl,
    const float* __restrict__ dtw, const float* __restrict__ dtb,
    const float* __restrict__ A_log, const float* __restrict__ hinit,
    const float* __restrict__ Dp, const float* __restrict__ zs,
    __hip_bfloat16* __restrict__ yfb)
{
    __shared__ float xs[CHUNK * 40];
    const int c = blockIdx.x, d = threadIdx.x;
    const int t0 = c * CHUNK;
    for (int k = d; k < CHUNK * 40; k += 256) xs[k] = xdbl[(size_t)t0 * 40 + k];
    __syncthreads();
    const f32x4 wa = *(const f32x4*)(dtw + d * 8);
    const f32x4 wb = *(const f32x4*)(dtw + d * 8 + 4);
    const float dbias = dtb[d];
    float An[16], h[16];
    #pragma unroll
    for (int n = 0; n < 16; ++n) {
        An[n] = -expf(A_log[d * 16 + n]);
        h[n] = hinit[(size_t)c * 4096 + (size_t)d * 16 + n];
    }
    const float Dv = Dp[d];
    for (int tt = 0; tt < CHUNK; ++tt) {
        const float* xr = xs + tt * 40;
        float dr = dbias + xr[0]*wa[0] + xr[1]*wa[1] + xr[2]*wa[2] + xr[3]*wa[3]
                         + xr[4]*wb[0] + xr[5]*wb[1] + xr[6]*wb[2] + xr[7]*wb[3];
        float dt = (dr > 20.0f) ? dr : logf(1.0f + expf(dr));
        float xv = xf[(size_t)(t0 + tt) * 256 + d];
        float dtx = dt * xv;
        float y = 0.0f;
        #pragma unroll
        for (int n = 0; n < 16; ++n) {
            float a = __expf(dt * An[n]);
            h[n] = a * h[n] + dtx * xr[8 + n];
            y += h[n] * xr[24 + n];
        }
        float outv = (y + Dv * xv) * zs[(size_t)(t0 + tt) * 256 + d];
        yfb[(size_t)(t0 + tt) * 256 + d] = __float2bfloat16(outv);
    }
}

extern "C" void kernel_launch(void* const* d_in, const int* in_sizes, int n_in,
                              void* d_out, int out_size, void* d_ws, size_t ws_size,
                              hipStream_t stream)
{
    const float* enc        = (const float*)d_in[0];
    const float* dec        = (const float*)d_in[1];
    const float* in_proj_w  = (const float*)d_in[2];
    const float* conv_w     = (const float*)d_in[3];
    const float* conv_b     = (const float*)d_in[4];
    const float* x_proj_w   = (const float*)d_in[5];
    const float* dt_proj_w  = (const float*)d_in[6];
    const float* dt_proj_b  = (const float*)d_in[7];
    const float* A_log      = (const float*)d_in[8];
    const float* Dp         = (const float*)d_in[9];
    const float* out_proj_w = (const float*)d_in[10];
    const float* q_w        = (const float*)d_in[11];
    const float* q_b        = (const float*)d_in[12];
    const float* k_w        = (const float*)d_in[13];
    const float* k_b        = (const float*)d_in[14];

    char* ws = (char*)d_ws;
    size_t off = 0;
    auto alloc = [&](size_t bytes) -> void* {
        void* p = ws + off;
        off += (bytes + 255) & ~(size_t)255;
        return p;
    };
    __hip_bfloat16* wib  = (__hip_bfloat16*)alloc((size_t)512 * 128 * 2);
    __hip_bfloat16* wxb  = (__hip_bfloat16*)alloc((size_t)40 * 256 * 2);
    __hip_bfloat16* kwb  = (__hip_bfloat16*)alloc((size_t)256 * 128 * 2);
    __hip_bfloat16* wcb  = (__hip_bfloat16*)alloc((size_t)256 * 256 * 2);
    float* xf    = (float*)alloc((size_t)8192 * 256 * 4);
    __hip_bfloat16* xb = (__hip_bfloat16*)alloc((size_t)8192 * 256 * 2);
    float* zs    = (float*)alloc((size_t)8192 * 256 * 4);
    float* xdbl  = (float*)alloc((size_t)8192 * 40 * 4);
    float* P     = (float*)alloc((size_t)NCHUNK * 4096 * 4);
    float* Ssum  = (float*)alloc((size_t)NCHUNK * 4096 * 4);
    float* hinit = (float*)alloc((size_t)NCHUNK * 4096 * 4);
    __hip_bfloat16* yfb = (__hip_bfloat16*)alloc((size_t)8192 * 256 * 2);
    __hip_bfloat16* qbm = (__hip_bfloat16*)alloc((size_t)8192 * 256 * 2);
    __hip_bfloat16* kbm = (__hip_bfloat16*)alloc((size_t)8192 * 256 * 2);
    float* partial = (float*)alloc((size_t)128 * 8192 * 4);
    float* invZ    = (float*)alloc((size_t)8192 * 4);
    (void)ws_size;

    // weight preps (converts + Wc fold)
    prep_k<<<680, 256, 0, stream>>>(in_proj_w, x_proj_w, k_w, q_w, out_proj_w,
                                    wib, wxb, kwb, wcb);

    // in_proj GEMM (fp32 A) + fused conv/silu epilogue -> xf, xb, zs
    {
        dim3 g(512 / 64, 8192 / 64);
        gemm_f32a_k<0><<<g, 256, 0, stream>>>(dec, wib, conv_w, conv_b,
                                              xf, xb, zs, 8192, 512, 128);
    }
    // x_dbl = x @ x_proj_w^T   [8192, 40]
    {
        dim3 g(1, 8192 / 64);
        gemm_bt_k<0, 0><<<g, 256, 0, stream>>>(xb, wxb, xdbl, nullptr, nullptr, 8192, 40, 256);
    }
    // selective scan (3-phase, dt fused)
    scan_chunk_k<<<NCHUNK, 256, 0, stream>>>(xf, xdbl, dt_proj_w, dt_proj_b, A_log, P, Ssum);
    scan_carry_k<<<16, 256, 0, stream>>>(P, Ssum, hinit);
    scan_final_k<<<NCHUNK, 256, 0, stream>>>(xf, xdbl, dt_proj_w, dt_proj_b, A_log,
                                             hinit, Dp, zs, yfb);

    // queries = yfin @ Wc^T + q_b  -> bf16 [8192,256]
    {
        dim3 g(256 / 64, 8192 / 64);
        gemm_bt_k<1, 1><<<g, 256, 0, stream>>>(yfb, wcb, nullptr, qbm, q_b, 8192, 256, 256);
    }
    // keys = enc(fp32) @ k_w^T + k_b  -> bf16 [8192,256]
    {
        dim3 g(256 / 64, 8192 / 64);
        gemm_f32a_k<1><<<g, 256, 0, stream>>>(enc, kwb, k_b, nullptr,
                                              nullptr, kbm, nullptr, 8192, 256, 128);
    }

    // fused scores+softmax: S1 (sum of exp) -> reduce -> S2 (write p)
    {
        dim3 g(8192 / 256, 8192 / 256);
        scores_k<0><<<g, 512, 0, stream>>>(qbm, kbm, partial, nullptr);
        rowsum_inv_k<<<8192 / 256, 256, 0, stream>>>(partial, invZ);
        scores_k<1><<<g, 512, 0, stream>>>(qbm, kbm, (float*)d_out, invZ);
    }
}

// Round 7
// 236.515 us; speedup vs baseline: 1.1184x; 1.1184x over previous
//
#include <hip/hip_runtime.h>
#include <hip/hip_bf16.h>

typedef __attribute__((ext_vector_type(8))) short bf16x8;
typedef __attribute__((ext_vector_type(4))) float f32x4;

#define CHUNK 32
#define NCHUNK 256   // 8192 / CHUNK

__device__ __forceinline__ void gload16(const void* g, void* l) {
    __builtin_amdgcn_global_load_lds(
        (const __attribute__((address_space(1))) void*)g,
        (__attribute__((address_space(3))) void*)l,
        16, 0, 0);
}

__device__ __forceinline__ float silu_f(float v) { return v / (1.0f + __expf(-v)); }

// ---------------- prep: small-weight converts + Wc = q_w @ out_proj ----------------
__global__ __launch_bounds__(256) void prep_k(
    const float* __restrict__ in_proj_w, const float* __restrict__ x_proj_w,
    const float* __restrict__ k_w, const float* __restrict__ q_w,
    const float* __restrict__ out_proj_w,
    __hip_bfloat16* __restrict__ wib, __hip_bfloat16* __restrict__ wxb,
    __hip_bfloat16* __restrict__ kwb, __hip_bfloat16* __restrict__ wcb)
{
    const int b = blockIdx.x, t = threadIdx.x;
    if (b < 424) {
        int idx = b * 256 + t;
        if (idx < 65536)      wib[idx]         = __float2bfloat16(in_proj_w[idx]);
        else if (idx < 75776) wxb[idx - 65536] = __float2bfloat16(x_proj_w[idx - 65536]);
        else                  kwb[idx - 75776] = __float2bfloat16(k_w[idx - 75776]);
    } else {
        const int hh = b - 424;
        float acc = 0.0f;
        for (int m = 0; m < 128; ++m) acc += q_w[hh * 128 + m] * out_proj_w[m * 256 + t];
        wcb[hh * 256 + t] = __float2bfloat16(acc);
    }
}

// ---------------- generic bf16 A[M,K] @ B[N,K]^T -> C[M,N] (small GEMMs) ----------------
template<int OUT_BF16, int HAS_BIAS>
__global__ __launch_bounds__(256) void gemm_bt_k(
    const __hip_bfloat16* __restrict__ A,
    const __hip_bfloat16* __restrict__ B,
    float* __restrict__ Cf, __hip_bfloat16* __restrict__ Cb,
    const float* __restrict__ bias, int M, int N, int K)
{
    __shared__ __hip_bfloat16 As[64][40];
    __shared__ __hip_bfloat16 Bs[64][40];
    const int tid  = threadIdx.x;
    const int wave = tid >> 6;
    const int lane = tid & 63;
    const int wm = (wave >> 1) << 5;
    const int wn = (wave & 1) << 5;
    const long bm = (long)blockIdx.y << 6;
    const long bn = (long)blockIdx.x << 6;

    f32x4 acc[2][2] = {{{0.f,0.f,0.f,0.f},{0.f,0.f,0.f,0.f}},
                       {{0.f,0.f,0.f,0.f},{0.f,0.f,0.f,0.f}}};

    const int sr = tid >> 2;
    const int sc = (tid & 3) << 3;
    const int lr = lane & 15;
    const int kg = (lane >> 4) << 3;

    for (int k0 = 0; k0 < K; k0 += 32) {
        {
            long ar = bm + sr;
            bf16x8 av = {0,0,0,0,0,0,0,0};
            if (ar < M) av = *(const bf16x8*)(A + ar * K + k0 + sc);
            *(bf16x8*)&As[sr][sc] = av;
            long br = bn + sr;
            bf16x8 bv = {0,0,0,0,0,0,0,0};
            if (br < N) bv = *(const bf16x8*)(B + br * K + k0 + sc);
            *(bf16x8*)&Bs[sr][sc] = bv;
        }
        __syncthreads();
        bf16x8 a0 = *(const bf16x8*)&As[wm + lr][kg];
        bf16x8 a1 = *(const bf16x8*)&As[wm + 16 + lr][kg];
        bf16x8 b0 = *(const bf16x8*)&Bs[wn + lr][kg];
        bf16x8 b1 = *(const bf16x8*)&Bs[wn + 16 + lr][kg];
        acc[0][0] = __builtin_amdgcn_mfma_f32_16x16x32_bf16(a0, b0, acc[0][0], 0, 0, 0);
        acc[0][1] = __builtin_amdgcn_mfma_f32_16x16x32_bf16(a0, b1, acc[0][1], 0, 0, 0);
        acc[1][0] = __builtin_amdgcn_mfma_f32_16x16x32_bf16(a1, b0, acc[1][0], 0, 0, 0);
        acc[1][1] = __builtin_amdgcn_mfma_f32_16x16x32_bf16(a1, b1, acc[1][1], 0, 0, 0);
        __syncthreads();
    }
    const int rg = (lane >> 4) << 2;
    #pragma unroll
    for (int i = 0; i < 2; ++i)
      #pragma unroll
      for (int j = 0; j < 2; ++j)
        #pragma unroll
        for (int r = 0; r < 4; ++r) {
            long row = bm + wm + i * 16 + rg + r;
            long col = bn + wn + j * 16 + lr;
            if (row < M && col < N) {
                float v = acc[i][j][r];
                if (HAS_BIAS) v += bias[col];
                if (OUT_BF16) Cb[row * N + col] = __float2bfloat16(v);
                else          Cf[row * N + col] = v;
            }
        }
}

// ---------------- fp32-A GEMM: A[M,K]f32 @ B[N,K]^T, staged convert to bf16 ----------------
template<int EPI>
__global__ __launch_bounds__(256) void gemm_f32a_k(
    const float* __restrict__ A, const __hip_bfloat16* __restrict__ B,
    const float* __restrict__ w0, const float* __restrict__ w1,
    float* __restrict__ xf, __hip_bfloat16* __restrict__ ob, float* __restrict__ zs,
    int M, int N, int K)
{
    __shared__ __hip_bfloat16 As[64][40];
    __shared__ __hip_bfloat16 Bs[64][40];
    const int tid  = threadIdx.x;
    const int wave = tid >> 6;
    const int lane = tid & 63;
    const int wm = (wave >> 1) << 5;
    const int wn = (wave & 1) << 5;
    const long bm = (long)blockIdx.y << 6;
    const long bn = (long)blockIdx.x << 6;

    f32x4 acc[2][2] = {{{0.f,0.f,0.f,0.f},{0.f,0.f,0.f,0.f}},
                       {{0.f,0.f,0.f,0.f},{0.f,0.f,0.f,0.f}}};

    const int sr = tid >> 2;
    const int sc = (tid & 3) << 3;
    const int lr = lane & 15;
    const int kg = (lane >> 4) << 3;

    for (int k0 = 0; k0 < K; k0 += 32) {
        {
            long ar = bm + sr;
            f32x4 x0 = *(const f32x4*)(A + ar * K + k0 + sc);
            f32x4 x1 = *(const f32x4*)(A + ar * K + k0 + sc + 4);
            union { bf16x8 v; __hip_bfloat16 h[8]; } u;
            u.h[0] = __float2bfloat16(x0[0]); u.h[1] = __float2bfloat16(x0[1]);
            u.h[2] = __float2bfloat16(x0[2]); u.h[3] = __float2bfloat16(x0[3]);
            u.h[4] = __float2bfloat16(x1[0]); u.h[5] = __float2bfloat16(x1[1]);
            u.h[6] = __float2bfloat16(x1[2]); u.h[7] = __float2bfloat16(x1[3]);
            *(bf16x8*)&As[sr][sc] = u.v;
            long br = bn + sr;
            bf16x8 bv = {0,0,0,0,0,0,0,0};
            if (br < N) bv = *(const bf16x8*)(B + br * K + k0 + sc);
            *(bf16x8*)&Bs[sr][sc] = bv;
        }
        __syncthreads();
        bf16x8 a0 = *(const bf16x8*)&As[wm + lr][kg];
        bf16x8 a1 = *(const bf16x8*)&As[wm + 16 + lr][kg];
        bf16x8 b0 = *(const bf16x8*)&Bs[wn + lr][kg];
        bf16x8 b1 = *(const bf16x8*)&Bs[wn + 16 + lr][kg];
        acc[0][0] = __builtin_amdgcn_mfma_f32_16x16x32_bf16(a0, b0, acc[0][0], 0, 0, 0);
        acc[0][1] = __builtin_amdgcn_mfma_f32_16x16x32_bf16(a0, b1, acc[0][1], 0, 0, 0);
        acc[1][0] = __builtin_amdgcn_mfma_f32_16x16x32_bf16(a1, b0, acc[1][0], 0, 0, 0);
        acc[1][1] = __builtin_amdgcn_mfma_f32_16x16x32_bf16(a1, b1, acc[1][1], 0, 0, 0);
        __syncthreads();
    }
    const int rg = (lane >> 4) << 2;
    #pragma unroll
    for (int i = 0; i < 2; ++i)
      #pragma unroll
      for (int j = 0; j < 2; ++j)
        #pragma unroll
        for (int r = 0; r < 4; ++r) {
            long row = bm + wm + i * 16 + rg + r;
            long col = bn + wn + j * 16 + lr;
            float v = acc[i][j][r];
            if (EPI == 0) {
                if (col < 256) {
                    float xv = v * w0[col] + w1[col];
                    float s = silu_f(xv);
                    xf[row * 256 + col] = s;
                    ob[row * 256 + col] = __float2bfloat16(s);
                } else {
                    zs[row * 256 + col - 256] = silu_f(v);
                }
            } else {
                ob[row * N + col] = __float2bfloat16(v + w0[col]);
            }
        }
}

// ---------------- fused scores+softmax: 128x128 tile, BK=64, gload_lds + XOR swizzle ----
// 2D grid (bn fast): natural dispatch gives each XCD a stable bn%8 K-slice (L2-resident)
// and a hot Q-panel per bm row. Do NOT remap (r4 post-mortem: remap = 7x L3 traffic).
// Do NOT use 256^2 8-wave dbuf here (r6 post-mortem: 1 block/CU + 4 K-steps = exposed stalls).
template<int PASS>
__global__ __launch_bounds__(256) void scores_k(
    const __hip_bfloat16* __restrict__ Q, const __hip_bfloat16* __restrict__ Kb,
    float* __restrict__ out, const float* __restrict__ invZ)
{
    __shared__ alignas(16) char Asb[128 * 128];
    __shared__ alignas(16) char Bsb[128 * 128];
    const int tid = threadIdx.x, wave = tid >> 6, lane = tid & 63;
    const int bm = blockIdx.y << 7, bn = blockIdx.x << 7;
    const int wm = (wave >> 1) << 6, wn = (wave & 1) << 6;
    const int K = 256;

    f32x4 acc[4][4];
    #pragma unroll
    for (int i = 0; i < 4; ++i)
      #pragma unroll
      for (int j = 0; j < 4; ++j)
        acc[i][j] = (f32x4){0.f, 0.f, 0.f, 0.f};

    for (int k0 = 0; k0 < 256; k0 += 64) {
        #pragma unroll
        for (int c = 0; c < 4; ++c) {
            const int base = (wave * 4 + c) * 1024;
            const int o = base + lane * 16;
            const int q = o ^ (((o >> 7) & 7) << 4);   // pre-swizzled source (involution)
            const int row = q >> 7, col = (q & 127) >> 1;
            gload16(Q  + (size_t)(bm + row) * K + k0 + col, Asb + base);
            gload16(Kb + (size_t)(bn + row) * K + k0 + col, Bsb + base);
        }
        __syncthreads();
        #pragma unroll
        for (int ks = 0; ks < 2; ++ks) {
            bf16x8 af[4], bfr[4];
            const int cb = ks * 64 + ((lane >> 4) << 4);
            #pragma unroll
            for (int i = 0; i < 4; ++i) {
                const int ra = wm + i * 16 + (lane & 15);
                af[i]  = *(const bf16x8*)(Asb + ((ra * 128 + cb) ^ ((ra & 7) << 4)));
                const int rb = wn + i * 16 + (lane & 15);
                bfr[i] = *(const bf16x8*)(Bsb + ((rb * 128 + cb) ^ ((rb & 7) << 4)));
            }
            #pragma unroll
            for (int i = 0; i < 4; ++i)
              #pragma unroll
              for (int j = 0; j < 4; ++j)
                acc[i][j] = __builtin_amdgcn_mfma_f32_16x16x32_bf16(af[i], bfr[j], acc[i][j], 0, 0, 0);
        }
        __syncthreads();
    }

    const int lr = lane & 15, rg = (lane >> 4) << 2;
    if (PASS == 0) {
        #pragma unroll
        for (int i = 0; i < 4; ++i) {
            #pragma unroll
            for (int r = 0; r < 4; ++r) {
                float s = __expf(acc[i][0][r]) + __expf(acc[i][1][r])
                        + __expf(acc[i][2][r]) + __expf(acc[i][3][r]);
                #pragma unroll
                for (int o = 1; o < 16; o <<= 1) s += __shfl_xor(s, o, 64);
                if (lr == 0)
                    out[(size_t)(blockIdx.x * 2 + (wave & 1)) * 8192
                        + bm + wm + i * 16 + rg + r] = s;
            }
        }
    } else {
        #pragma unroll
        for (int i = 0; i < 4; ++i)
          #pragma unroll
          for (int r = 0; r < 4; ++r) {
            const int row = bm + wm + i * 16 + rg + r;
            const float iz = invZ[row];
            #pragma unroll
            for (int j = 0; j < 4; ++j)
                __builtin_nontemporal_store(__expf(acc[i][j][r]) * iz,
                    out + (size_t)row * 8192 + bn + wn + j * 16 + lr);
          }
    }
}

// ---------------- rowsum -> reciprocal ----------------
__global__ __launch_bounds__(256) void rowsum_inv_k(
    const float* __restrict__ partial, float* __restrict__ invZ)
{
    const int row = blockIdx.x * 256 + threadIdx.x;
    float s = 0.0f;
    for (int c = 0; c < 128; ++c) s += partial[(size_t)c * 8192 + row];
    invZ[row] = 1.0f / s;
}

// ---------------- scan phase A: per-chunk affine summaries (dt fused) ----------------
__global__ __launch_bounds__(256) void scan_chunk_k(
    const float* __restrict__ xf, const float* __restrict__ xdbl,
    const float* __restrict__ dtw, const float* __restrict__ dtb,
    const float* __restrict__ A_log,
    float* __restrict__ P, float* __restrict__ S)
{
    __shared__ float xs[CHUNK * 40];
    const int c = blockIdx.x, d = threadIdx.x;
    const int t0 = c * CHUNK;
    for (int k = d; k < CHUNK * 40; k += 256) xs[k] = xdbl[(size_t)t0 * 40 + k];
    __syncthreads();
    const f32x4 wa = *(const f32x4*)(dtw + d * 8);
    const f32x4 wb = *(const f32x4*)(dtw + d * 8 + 4);
    const float dbias = dtb[d];
    float An[16], Pv[16], Sv[16];
    #pragma unroll
    for (int n = 0; n < 16; ++n) { An[n] = -expf(A_log[d * 16 + n]); Pv[n] = 1.0f; Sv[n] = 0.0f; }
    for (int tt = 0; tt < CHUNK; ++tt) {
        const float* xr = xs + tt * 40;
        float dr = dbias + xr[0]*wa[0] + xr[1]*wa[1] + xr[2]*wa[2] + xr[3]*wa[3]
                         + xr[4]*wb[0] + xr[5]*wb[1] + xr[6]*wb[2] + xr[7]*wb[3];
        float dt = (dr > 20.0f) ? dr : logf(1.0f + expf(dr));
        float xv = xf[(size_t)(t0 + tt) * 256 + d];
        float dtx = dt * xv;
        #pragma unroll
        for (int n = 0; n < 16; ++n) {
            float a = __expf(dt * An[n]);
            Pv[n] *= a;
            Sv[n] = a * Sv[n] + dtx * xr[8 + n];
        }
    }
    size_t base = (size_t)c * 4096 + (size_t)d * 16;
    #pragma unroll
    for (int n = 0; n < 16; ++n) { P[base + n] = Pv[n]; S[base + n] = Sv[n]; }
}

// ---------------- scan phase B: carry across chunks ----------------
// 64 blocks x 64 threads: spreads the 4096 serial channel-scans over 64 CUs
// (16x256 put all BW on 16 CUs -> ~25us; this is ~4x the bandwidth).
__global__ __launch_bounds__(64) void scan_carry_k(
    const float* __restrict__ P, const float* __restrict__ S, float* __restrict__ hinit)
{
    const int ch = blockIdx.x * 64 + threadIdx.x;
    float h = 0.0f;
    for (int c = 0; c < NCHUNK; c += 8) {
        float p[8], s[8];
        #pragma unroll
        for (int j = 0; j < 8; ++j) {
            p[j] = P[(size_t)(c + j) * 4096 + ch];
            s[j] = S[(size_t)(c + j) * 4096 + ch];
        }
        #pragma unroll
        for (int j = 0; j < 8; ++j) {
            hinit[(size_t)(c + j) * 4096 + ch] = h;
            h = p[j] * h + s[j];
        }
    }
}

// ---------------- scan phase C: replay + gate (dt fused) -> yfin bf16 ----------------
__global__ __launch_bounds__(256) void scan_final_k(
    const float* __restrict__ xf, const float* __restrict__ xdbl,
    const float* __restrict__ dtw, const float* __restrict__ dtb,
    const float* __restrict__ A_log, const float* __restrict__ hinit,
    const float* __restrict__ Dp, const float* __restrict__ zs,
    __hip_bfloat16* __restrict__ yfb)
{
    __shared__ float xs[CHUNK * 40];
    const int c = blockIdx.x, d = threadIdx.x;
    const int t0 = c * CHUNK;
    for (int k = d; k < CHUNK * 40; k += 256) xs[k] = xdbl[(size_t)t0 * 40 + k];
    __syncthreads();
    const f32x4 wa = *(const f32x4*)(dtw + d * 8);
    const f32x4 wb = *(const f32x4*)(dtw + d * 8 + 4);
    const float dbias = dtb[d];
    float An[16], h[16];
    #pragma unroll
    for (int n = 0; n < 16; ++n) {
        An[n] = -expf(A_log[d * 16 + n]);
        h[n] = hinit[(size_t)c * 4096 + (size_t)d * 16 + n];
    }
    const float Dv = Dp[d];
    for (int tt = 0; tt < CHUNK; ++tt) {
        const float* xr = xs + tt * 40;
        float dr = dbias + xr[0]*wa[0] + xr[1]*wa[1] + xr[2]*wa[2] + xr[3]*wa[3]
                         + xr[4]*wb[0] + xr[5]*wb[1] + xr[6]*wb[2] + xr[7]*wb[3];
        float dt = (dr > 20.0f) ? dr : logf(1.0f + expf(dr));
        float xv = xf[(size_t)(t0 + tt) * 256 + d];
        float dtx = dt * xv;
        float y = 0.0f;
        #pragma unroll
        for (int n = 0; n < 16; ++n) {
            float a = __expf(dt * An[n]);
            h[n] = a * h[n] + dtx * xr[8 + n];
            y += h[n] * xr[24 + n];
        }
        float outv = (y + Dv * xv) * zs[(size_t)(t0 + tt) * 256 + d];
        yfb[(size_t)(t0 + tt) * 256 + d] = __float2bfloat16(outv);
    }
}

extern "C" void kernel_launch(void* const* d_in, const int* in_sizes, int n_in,
                              void* d_out, int out_size, void* d_ws, size_t ws_size,
                              hipStream_t stream)
{
    const float* enc        = (const float*)d_in[0];
    const float* dec        = (const float*)d_in[1];
    const float* in_proj_w  = (const float*)d_in[2];
    const float* conv_w     = (const float*)d_in[3];
    const float* conv_b     = (const float*)d_in[4];
    const float* x_proj_w   = (const float*)d_in[5];
    const float* dt_proj_w  = (const float*)d_in[6];
    const float* dt_proj_b  = (const float*)d_in[7];
    const float* A_log      = (const float*)d_in[8];
    const float* Dp         = (const float*)d_in[9];
    const float* out_proj_w = (const float*)d_in[10];
    const float* q_w        = (const float*)d_in[11];
    const float* q_b        = (const float*)d_in[12];
    const float* k_w        = (const float*)d_in[13];
    const float* k_b        = (const float*)d_in[14];

    char* ws = (char*)d_ws;
    size_t off = 0;
    auto alloc = [&](size_t bytes) -> void* {
        void* p = ws + off;
        off += (bytes + 255) & ~(size_t)255;
        return p;
    };
    __hip_bfloat16* wib  = (__hip_bfloat16*)alloc((size_t)512 * 128 * 2);
    __hip_bfloat16* wxb  = (__hip_bfloat16*)alloc((size_t)40 * 256 * 2);
    __hip_bfloat16* kwb  = (__hip_bfloat16*)alloc((size_t)256 * 128 * 2);
    __hip_bfloat16* wcb  = (__hip_bfloat16*)alloc((size_t)256 * 256 * 2);
    float* xf    = (float*)alloc((size_t)8192 * 256 * 4);
    __hip_bfloat16* xb = (__hip_bfloat16*)alloc((size_t)8192 * 256 * 2);
    float* zs    = (float*)alloc((size_t)8192 * 256 * 4);
    float* xdbl  = (float*)alloc((size_t)8192 * 40 * 4);
    float* P     = (float*)alloc((size_t)NCHUNK * 4096 * 4);
    float* Ssum  = (float*)alloc((size_t)NCHUNK * 4096 * 4);
    float* hinit = (float*)alloc((size_t)NCHUNK * 4096 * 4);
    __hip_bfloat16* yfb = (__hip_bfloat16*)alloc((size_t)8192 * 256 * 2);
    __hip_bfloat16* qbm = (__hip_bfloat16*)alloc((size_t)8192 * 256 * 2);
    __hip_bfloat16* kbm = (__hip_bfloat16*)alloc((size_t)8192 * 256 * 2);
    float* partial = (float*)alloc((size_t)128 * 8192 * 4);
    float* invZ    = (float*)alloc((size_t)8192 * 4);
    (void)ws_size;

    // weight preps (converts + Wc fold)
    prep_k<<<680, 256, 0, stream>>>(in_proj_w, x_proj_w, k_w, q_w, out_proj_w,
                                    wib, wxb, kwb, wcb);

    // in_proj GEMM (fp32 A) + fused conv/silu epilogue -> xf, xb, zs
    {
        dim3 g(512 / 64, 8192 / 64);
        gemm_f32a_k<0><<<g, 256, 0, stream>>>(dec, wib, conv_w, conv_b,
                                              xf, xb, zs, 8192, 512, 128);
    }
    // x_dbl = x @ x_proj_w^T   [8192, 40]
    {
        dim3 g(1, 8192 / 64);
        gemm_bt_k<0, 0><<<g, 256, 0, stream>>>(xb, wxb, xdbl, nullptr, nullptr, 8192, 40, 256);
    }
    // selective scan (3-phase, dt fused)
    scan_chunk_k<<<NCHUNK, 256, 0, stream>>>(xf, xdbl, dt_proj_w, dt_proj_b, A_log, P, Ssum);
    scan_carry_k<<<64, 64, 0, stream>>>(P, Ssum, hinit);
    scan_final_k<<<NCHUNK, 256, 0, stream>>>(xf, xdbl, dt_proj_w, dt_proj_b, A_log,
                                             hinit, Dp, zs, yfb);

    // queries = yfin @ Wc^T + q_b  -> bf16 [8192,256]
    {
        dim3 g(256 / 64, 8192 / 64);
        gemm_bt_k<1, 1><<<g, 256, 0, stream>>>(yfb, wcb, nullptr, qbm, q_b, 8192, 256, 256);
    }
    // keys = enc(fp32) @ k_w^T + k_b  -> bf16 [8192,256]
    {
        dim3 g(256 / 64, 8192 / 64);
        gemm_f32a_k<1><<<g, 256, 0, stream>>>(enc, kwb, k_b, nullptr,
                                              nullptr, kbm, nullptr, 8192, 256, 128);
    }

    // fused scores+softmax: S1 (sum of exp) -> reduce -> S2 (write p)
    {
        dim3 g(8192 / 128, 8192 / 128);
        scores_k<0><<<g, 256, 0, stream>>>(qbm, kbm, partial, nullptr);
        rowsum_inv_k<<<8192 / 256, 256, 0, stream>>>(partial, invZ);
        scores_k<1><<<g, 256, 0, stream>>>(qbm, kbm, (float*)d_out, invZ);
    }
}